// Round 2
// baseline (215.307 us; speedup 1.0000x reference)
//
#include <hip/hip_runtime.h>

// DilatedAttention: b=2,h=16,s=8192,d=64; W=[4,8,16], R=[1,2,4] -> L=4 for all
// groups. A 32-position span is self-contained for all three groups.
// Inputs/outputs are FLOAT32 (per reference dtypes); compute in fp32.

#define SPAN 32
#define PD   68   // LDS row stride in floats: 68 mod 32 = 4 -> <=2-way conflicts (free)
#define D    64
#define S_SEQ 8192

__device__ __forceinline__ void acc_group(float4& acc, const float* lv,
                                          const float* pl, int prow, float wg,
                                          int kb, int stride, int dd) {
    float p0 = pl[prow * 4 + 0] * wg;
    float p1 = pl[prow * 4 + 1] * wg;
    float p2 = pl[prow * 4 + 2] * wg;
    float p3 = pl[prow * 4 + 3] * wg;
    const float* vr = &lv[kb * PD + dd];
    float4 v0 = *(const float4*)(vr);
    float4 v1 = *(const float4*)(vr + stride * PD);
    float4 v2 = *(const float4*)(vr + 2 * stride * PD);
    float4 v3 = *(const float4*)(vr + 3 * stride * PD);
    acc.x += p0 * v0.x + p1 * v1.x + p2 * v2.x + p3 * v3.x;
    acc.y += p0 * v0.y + p1 * v1.y + p2 * v2.y + p3 * v3.y;
    acc.z += p0 * v0.z + p1 * v1.z + p2 * v2.z + p3 * v3.z;
    acc.w += p0 * v0.w + p1 * v1.w + p2 * v2.w + p3 * v3.w;
}

__global__ __launch_bounds__(256) void dilated_attn_kernel(
    const float* __restrict__ q,
    const float* __restrict__ k,
    const float* __restrict__ v,
    const float* __restrict__ alpha,
    float* __restrict__ out) {
    __shared__ float lq[SPAN * PD];
    __shared__ float lk[SPAN * PD];
    __shared__ float lv[SPAN * PD];
    __shared__ float pl[224];  // 56 rows x 4 probs

    const int tid = threadIdx.x;
    const int nspan = S_SEQ / SPAN;                 // 256
    const int bh = blockIdx.x / nspan;
    const int span = blockIdx.x % nspan;
    const long long rowbase = (long long)bh * S_SEQ + (long long)span * SPAN;

    // softmax(alpha) over 3 groups (redundant per-thread, trivial)
    float a0 = alpha[0];
    float a1 = alpha[1];
    float a2 = alpha[2];
    float am = fmaxf(a0, fmaxf(a1, a2));
    float e0 = __expf(a0 - am), e1 = __expf(a1 - am), e2 = __expf(a2 - am);
    float inv = 1.0f / (e0 + e1 + e2);
    const float w0 = e0 * inv, w1 = e1 * inv, w2 = e2 * inv;

    // ---- Phase 1: stage q,k,v (32 rows x 64 f32) into LDS, coalesced float4 ----
    {
        const float4* q4 = (const float4*)q;
        const float4* k4 = (const float4*)k;
        const float4* v4 = (const float4*)v;
#pragma unroll
        for (int t = 0; t < 2; ++t) {
            const int idx = tid + 256 * t;          // 0..511
            const int row = idx >> 4;               // 0..31
            const int c4  = idx & 15;               // float4 chunk within row
            const long long gi = (rowbase + row) * (D / 4) + c4;
            *(float4*)&lq[row * PD + c4 * 4] = q4[gi];
            *(float4*)&lk[row * PD + c4 * 4] = k4[gi];
            *(float4*)&lv[row * PD + c4 * 4] = v4[gi];
        }
    }
    __syncthreads();

    // ---- Phase 2: 224 scores = 56 query rows x 4 keys; softmax over 4 lanes ----
    if (tid < 224) {
        const int row = tid >> 2;  // 0..55
        const int j   = tid & 3;
        int w, r, win, i;
        if (row < 32)      { w = 4;  r = 1; win = row >> 2;        i = row & 3; }
        else if (row < 48) { w = 8;  r = 2; win = (row - 32) >> 2; i = (row - 32) & 3; }
        else               { w = 16; r = 4; win = (row - 48) >> 2; i = (row - 48) & 3; }
        const int pq = win * w + i * r;
        const int pk = win * w + j * r;
        const float* qr = &lq[pq * PD];
        const float* kr = &lk[pk * PD];
        float s = 0.0f;
#pragma unroll
        for (int c = 0; c < 16; ++c) {
            float4 a = *(const float4*)&qr[c * 4];
            float4 b = *(const float4*)&kr[c * 4];
            s += a.x * b.x + a.y * b.y + a.z * b.z + a.w * b.w;
        }
        s *= 0.125f;  // d^-0.5
        float m = fmaxf(s, __shfl_xor(s, 1));
        m = fmaxf(m, __shfl_xor(m, 2));
        float p = __expf(s - m);
        float sum = p + __shfl_xor(p, 1);
        sum += __shfl_xor(sum, 2);
        pl[tid] = p / sum;   // pl[row*4 + j]
    }
    __syncthreads();

    // ---- Phase 3: PV + mix. Wave w handles positions pos ≡ w (mod 4) so the
    // group-participation predicate is wave-uniform (no divergence). ----
    const int wv   = tid >> 6;        // 0..3
    const int l    = tid & 63;
    const int dd   = (l & 15) << 2;   // d offset, float4 granule
    const int psub = l >> 4;          // 0..3

#pragma unroll
    for (int s2 = 0; s2 < 2; ++s2) {
        const int pos = wv + 16 * s2 + 4 * psub;   // pos % 4 == wv
        float4 acc = make_float4(0.f, 0.f, 0.f, 0.f);

        // group 0 (w=4, r=1): every position; prob row == pos
        acc_group(acc, lv, pl, pos, w0, pos & ~3, 1, dd);

        if ((wv & 1) == 0) {  // group 1 (w=8, r=2): pos even
            const int row = 32 + ((pos >> 3) << 2) + ((pos & 7) >> 1);
            acc_group(acc, lv, pl, row, w1, pos & ~7, 2, dd);
        }
        if (wv == 0) {        // group 2 (w=16, r=4): pos % 4 == 0
            const int row = 48 + ((pos >> 4) << 2) + ((pos & 15) >> 2);
            acc_group(acc, lv, pl, row, w2, pos & ~15, 4, dd);
        }

        *(float4*)&out[(rowbase + pos) * D + dd] = acc;
    }
}

extern "C" void kernel_launch(void* const* d_in, const int* in_sizes, int n_in,
                              void* d_out, int out_size, void* d_ws, size_t ws_size,
                              hipStream_t stream) {
    const float* q = (const float*)d_in[0];
    const float* k = (const float*)d_in[1];
    const float* v = (const float*)d_in[2];
    const float* alpha = (const float*)d_in[3];
    float* out = (float*)d_out;

    const int BH = in_sizes[0] / (S_SEQ * D);      // b*h = 32
    dim3 grid(BH * (S_SEQ / SPAN));                 // 8192 blocks
    dim3 block(256);
    hipLaunchKernelGGL(dilated_attn_kernel, grid, block, 0, stream,
                       q, k, v, alpha, out);
}